// Round 5
// baseline (151.785 us; speedup 1.0000x reference)
//
#include <hip/hip_runtime.h>
#include <hip/hip_bf16.h>

#define T_SEQ   2048
#define BATCH   2
#define DMODEL  1024
#define NHEADS  16
#define HDIM    64
#define WINDOW  128

typedef __attribute__((ext_vector_type(8))) short bf16x8;
typedef __attribute__((ext_vector_type(4))) float f32x4;

#define LGKM(n)  asm volatile("s_waitcnt lgkmcnt(" #n ")" ::: "memory")
#define VMCNT(n) asm volatile("s_waitcnt vmcnt(" #n ")" ::: "memory")
#define SCHEDB() __builtin_amdgcn_sched_barrier(0)
#define BAR()    __builtin_amdgcn_s_barrier()

// async global->LDS 16B per lane; LDS dest = wave-uniform base + lane*16
__device__ inline void gld_lds16(const __hip_bfloat16* g, __hip_bfloat16* l) {
    __builtin_amdgcn_global_load_lds(
        (const __attribute__((address_space(1))) unsigned int*)g,
        (__attribute__((address_space(3))) unsigned int*)l, 16, 0, 0);
}

// inline-asm LDS read: invisible to the compiler's waitcnt pass (no auto
// vmcnt(0)/lgkm(0) drains). Manual counted waits own correctness.
__device__ inline bf16x8 ds_readb128(const __hip_bfloat16* p) {
    bf16x8 r;
    asm volatile("ds_read_b128 %0, %1"
                 : "=v"(r)
                 : "v"((const __attribute__((address_space(3))) __hip_bfloat16*)p));
    return r;
}

// fp32 -> bf16 bulk convert, exact 1D grid: lid<2048 -> x (4M elems),
// else 512 blocks per weight slot (1M each).
__global__ __launch_bounds__(256) void cvt_kernel(
    const float* __restrict__ x,  const float* __restrict__ Wq,
    const float* __restrict__ Wk, const float* __restrict__ Wv,
    const float* __restrict__ Wo,
    __hip_bfloat16* __restrict__ xb, __hip_bfloat16* __restrict__ Wb)
{
    const int lid = blockIdx.x;
    const float* src;
    __hip_bfloat16* dst;
    int blk;
    if (lid < 2048) { src = x; dst = xb; blk = lid; }
    else {
        int slot = (lid - 2048) >> 9;           // 0..3
        blk = (lid - 2048) & 511;
        src = (slot == 0) ? Wq : (slot == 1) ? Wk : (slot == 2) ? Wv : Wo;
        dst = Wb + (size_t)slot * 1024 * 1024;
    }
    int i = (blk * 256 + threadIdx.x) * 8;
    float4 a = *(const float4*)(src + i);
    float4 b = *(const float4*)(src + i + 4);
    __hip_bfloat16 pk[8] = {
        __float2bfloat16(a.x), __float2bfloat16(a.y),
        __float2bfloat16(a.z), __float2bfloat16(a.w),
        __float2bfloat16(b.x), __float2bfloat16(b.y),
        __float2bfloat16(b.z), __float2bfloat16(b.w)};
    *(uint4*)(dst + i) = *(uint4*)pk;
}

// ---------------------------------------------------------------------------
// QKV GEMM v5: 128x128 tile, 4 waves (64x64/wave), BK=64, 2-buffer 64KB LDS
// -> 2 BLOCKS RESIDENT PER CU (the R4 post-mortem's missing mechanism:
// independent blocks run in antiphase, so one block's LDS-read burst fills
// the other's MFMA shadow — barrier lockstep within a block stops mattering).
// Grid 768 (32 bm x 24 bn), bijective XCD remap (96 blocks/XCD).
// LDS layout: row = 64 elems (128 B), 8-chunk rotation — slot s of row r
// holds k-chunk (s-r)&7, read slot (kc+r)&7. Verified conflict-free
// (R1-R3: SQ_LDS_BANK_CONFLICT = 0; 16 rows hit all 8 bank-groups x2).
// Per K-tile per wave: 8 gld (stage next) + 16 ds_read + 32 MFMA, gates:
//   LGKM(8)  before MFMA kk0 (its 8 reads = oldest; kk1's 8 in flight)
//   VMCNT(0) after MFMA kk0  (stage issued ~500 cyc earlier, L2-resident)
//   LGKM(0)  before barrier  (kk1 reads old -> cheap; REQUIRED so the next
//            tile's DMA can't overwrite a buffer with reads still queued)
//   BAR      publishes staged buffer; tail reads (next kk0) follow it.
// Hazard audit: STAGE(t+1)->S[nxt]; last reads of S[nxt] were tile t-1's
// kk1 reads, retired at t-1's LGKM(0) before its BAR, which precedes this
// STAGE in every wave. Tail reads target S[cur] (disjoint). Rule-18
// SCHEDB() after each gating lgkm pins MFMA clusters behind their gate.
// ---------------------------------------------------------------------------
__global__ __launch_bounds__(256, 2) void gemm_qkv(
    const __hip_bfloat16* __restrict__ A,
    const __hip_bfloat16* __restrict__ Wp,   // packed [Wq;Wk;Wv] = [3072,1024]
    __hip_bfloat16* __restrict__ C0,
    __hip_bfloat16* __restrict__ C1,
    __hip_bfloat16* __restrict__ C2)
{
    const int lid   = blockIdx.x;
    const int wgid  = (lid & 7) * 96 + (lid >> 3);   // 768 % 8 == 0: bijective
    const int bn    = wgid % 24;
    const int bm    = wgid / 24;
    const int m0    = bm * 128;
    const int n0    = bn * 128;
    const int z     = n0 >> 10;          // 0=Q 1=K 2=V (128 | 1024: no straddle)
    const int cbase = n0 & 1023;

    __shared__ __hip_bfloat16 S[2][2][128 * 64];   // [buf][A=0/B=1], 64 KiB

    const int t    = threadIdx.x;
    const int lane = t & 63;
    const int wv   = t >> 6;       // wave 0..3
    const int lrow = lane & 15;
    const int quad = lane >> 4;
    const int wm   = (wv >> 1) * 64;
    const int wn   = (wv & 1) * 64;
    const int drow = lane >> 3;
    const int sl   = lane & 7;

    f32x4 acc[4][4];
#pragma unroll
    for (int i = 0; i < 4; ++i)
#pragma unroll
        for (int j = 0; j < 4; ++j)
            acc[i][j] = (f32x4){0.f, 0.f, 0.f, 0.f};

    // stage one K-tile (A 128x64 + B 128x64): 4+4 gld insts per wave
    auto STAGE = [&](int tile, int buf) {
        const int k0 = tile << 6;
#pragma unroll
        for (int inst = 0; inst < 4; ++inst) {
            int r0 = wv * 32 + inst * 8;
            int r  = r0 + drow;
            int gcx = (sl - r) & 7;
            gld_lds16(A + (size_t)(m0 + r) * DMODEL + k0 + gcx * 8,
                      &S[buf][0][r0 * 64]);
        }
#pragma unroll
        for (int inst = 0; inst < 4; ++inst) {
            int r0 = wv * 32 + inst * 8;
            int r  = r0 + drow;
            int gcx = (sl - r) & 7;
            gld_lds16(Wp + (size_t)(n0 + r) * DMODEL + k0 + gcx * 8,
                      &S[buf][1][r0 * 64]);
        }
    };

    auto RDA = [&](int buf, int mi, int kc) -> bf16x8 {
        int r = wm + mi * 16 + lrow;
        return ds_readb128(&S[buf][0][r * 64 + (((kc + r) & 7) << 3)]);
    };
    auto RDB = [&](int buf, int ni, int kc) -> bf16x8 {
        int r = wn + ni * 16 + lrow;
        return ds_readb128(&S[buf][1][r * 64 + (((kc + r) & 7) << 3)]);
    };

    bf16x8 a0[4], b0[4], a1[4], b1[4];

    // prologue
    STAGE(0, 0);
    VMCNT(0);
    BAR();
#pragma unroll
    for (int mi = 0; mi < 4; ++mi) a0[mi] = RDA(0, mi, quad);
#pragma unroll
    for (int ni = 0; ni < 4; ++ni) b0[ni] = RDB(0, ni, quad);

#pragma unroll 2
    for (int tt = 0; tt < 16; ++tt) {
        const int cur = tt & 1, nxt = cur ^ 1;
        if (tt < 15) STAGE(tt + 1, nxt);
        // kk1 reads (current buffer)
#pragma unroll
        for (int mi = 0; mi < 4; ++mi) a1[mi] = RDA(cur, mi, 4 + quad);
#pragma unroll
        for (int ni = 0; ni < 4; ++ni) b1[ni] = RDB(cur, ni, 4 + quad);
        LGKM(8); SCHEDB();
        __builtin_amdgcn_s_setprio(1);
#pragma unroll
        for (int mi = 0; mi < 4; ++mi)
#pragma unroll
            for (int ni = 0; ni < 4; ++ni)
                acc[mi][ni] = __builtin_amdgcn_mfma_f32_16x16x32_bf16(
                    a0[mi], b0[ni], acc[mi][ni], 0, 0, 0);
        __builtin_amdgcn_s_setprio(0);
        VMCNT(0);                 // stage(t+1) landed (issued ~1 group ago)
        LGKM(0); SCHEDB();        // kk1 reads retired (old; ~free)
        BAR();                    // publish staged buffer
        if (tt < 15) {
            // next tile's kk0 reads (freshly published buffer)
#pragma unroll
            for (int mi = 0; mi < 4; ++mi) a0[mi] = RDA(nxt, mi, quad);
#pragma unroll
            for (int ni = 0; ni < 4; ++ni) b0[ni] = RDB(nxt, ni, quad);
        }
        __builtin_amdgcn_s_setprio(1);
#pragma unroll
        for (int mi = 0; mi < 4; ++mi)
#pragma unroll
            for (int ni = 0; ni < 4; ++ni)
                acc[mi][ni] = __builtin_amdgcn_mfma_f32_16x16x32_bf16(
                    a1[mi], b1[ni], acc[mi][ni], 0, 0, 0);
        __builtin_amdgcn_s_setprio(0);
    }

    // per-head l2norm for Q,K (wave cols = exactly one 64-wide head)
    if (z != 2) {
#pragma unroll
        for (int mi = 0; mi < 4; ++mi) {
#pragma unroll
            for (int rr = 0; rr < 4; ++rr) {
                float ss = 0.f;
#pragma unroll
                for (int ni = 0; ni < 4; ++ni)
                    ss += acc[mi][ni][rr] * acc[mi][ni][rr];
                ss += __shfl_xor(ss, 1);
                ss += __shfl_xor(ss, 2);
                ss += __shfl_xor(ss, 4);
                ss += __shfl_xor(ss, 8);
                float inv = 1.0f / fmaxf(sqrtf(ss), 1e-6f);
#pragma unroll
                for (int ni = 0; ni < 4; ++ni)
                    acc[mi][ni][rr] *= inv;
            }
        }
    }

    __hip_bfloat16* C = (z == 0) ? C0 : (z == 1) ? C1 : C2;
    // C/D layout col=lane&15, row=quad*4+reg  [verified m89/m91]
#pragma unroll
    for (int mi = 0; mi < 4; ++mi) {
#pragma unroll
        for (int rr = 0; rr < 4; ++rr) {
            int row = m0 + wm + mi * 16 + quad * 4 + rr;
            __hip_bfloat16* Crow = C + (size_t)row * DMODEL + cbase + wn + lrow;
#pragma unroll
            for (int ni = 0; ni < 4; ++ni)
                Crow[ni * 16] = __float2bfloat16(acc[mi][ni][rr]);
        }
    }
}

// ---------------------------------------------------------------------------
// O-projection GEMM: 128x128 tile, 4 waves, half-K(32)/4-slot pipeline.
// R5 fix: rotation used (quad+r)&3 which parity-locks the bank group
// (4-way conflict, 2.36M measured). Now (quad+(r>>1))&3: rows 0..7 hit
// bank starts {0,16,4,20,8,24,12,28} — all 8 groups, 2 lanes each = free.
// Stage side matches: slot s holds chunk (s-(r>>1))&3.
// ---------------------------------------------------------------------------
__global__ __launch_bounds__(256, 2) void gemm_o(
    const __hip_bfloat16* __restrict__ A,
    const __hip_bfloat16* __restrict__ W,
    float* __restrict__ C)
{
    const int lid  = blockIdx.x;
    const int wgid = (lid & 7) * 32 + (lid >> 3);   // 256 blocks, 32/XCD
    const int bn   = wgid & 7;
    const int bm   = wgid >> 3;
    const int m0   = bm * 128;
    const int n0   = bn * 128;

    __shared__ __hip_bfloat16 S[4][2][128 * 32];    // 64 KiB

    const int t    = threadIdx.x;
    const int lane = t & 63;
    const int wv   = t >> 6;       // 0..3
    const int lrow = lane & 15;
    const int quad = lane >> 4;
    const int wm   = (wv >> 1) * 64;
    const int wn   = (wv & 1) * 64;

    f32x4 acc[4][4];
#pragma unroll
    for (int i = 0; i < 4; ++i)
#pragma unroll
        for (int j = 0; j < 4; ++j)
            acc[i][j] = (f32x4){0.f, 0.f, 0.f, 0.f};

    auto STAGE = [&](int h) {
        const int slot = h & 3;
        const int k0   = h * 32;
        const int r    = (lane >> 2);
        const int c    = lane & 3;
#pragma unroll
        for (int i = 0; i < 2; ++i) {
            int row0 = i * 64 + wv * 16;
            int row  = row0 + r;
            int gcx  = (c - (row >> 1)) & 3;
            gld_lds16(A + (size_t)(m0 + row) * DMODEL + k0 + gcx * 8,
                      &S[slot][0][row0 * 32]);
        }
#pragma unroll
        for (int i = 0; i < 2; ++i) {
            int row0 = i * 64 + wv * 16;
            int row  = row0 + r;
            int gcx  = (c - (row >> 1)) & 3;
            gld_lds16(W + (size_t)(n0 + row) * DMODEL + k0 + gcx * 8,
                      &S[slot][1][row0 * 32]);
        }
    };

    auto RD = [&](const __hip_bfloat16* base, int r) -> bf16x8 {
        return ds_readb128(base + r * 32 + (((quad + (r >> 1)) & 3) << 3));
    };

    bf16x8 a_[2][4], b_[2][4];

#define READS_O(P, H) { \
    const __hip_bfloat16* Sa = &S[(H) & 3][0][0]; \
    const __hip_bfloat16* Sb = &S[(H) & 3][1][0]; \
    _Pragma("unroll") for (int mi = 0; mi < 4; ++mi) \
        a_[P][mi] = RD(Sa, wm + mi * 16 + lrow); \
    _Pragma("unroll") for (int ni = 0; ni < 4; ++ni) \
        b_[P][ni] = RD(Sb, wn + ni * 16 + lrow); }

#define OBODY(H, P, PN, DO_STAGE, DO_READS, GATE) { \
    if (DO_STAGE) STAGE((H) + 3); \
    if (DO_READS) READS_O(PN, (H) + 1); \
    GATE; SCHEDB(); \
    __builtin_amdgcn_s_setprio(1); \
    _Pragma("unroll") for (int mi = 0; mi < 4; ++mi) \
    _Pragma("unroll") for (int ni = 0; ni < 4; ++ni) \
        acc[mi][ni] = __builtin_amdgcn_mfma_f32_16x16x32_bf16( \
            a_[P][mi], b_[P][ni], acc[mi][ni], 0, 0, 0); \
    __builtin_amdgcn_s_setprio(0); \
    VMCNT(4); BAR(); }

    STAGE(0); STAGE(1); STAGE(2);
    VMCNT(4);
    BAR();
    READS_O(0, 0);

    for (int it = 0; it < 15; ++it) {
        const int h = it * 2;
        OBODY(h,     0, 1, true,      true, LGKM(8));
        OBODY(h + 1, 1, 0, (it < 14), true, LGKM(8));
    }
    OBODY(30, 0, 1, false, true,  LGKM(8));
    OBODY(31, 1, 0, false, false, LGKM(0));

#undef OBODY
#undef READS_O

#pragma unroll
    for (int mi = 0; mi < 4; ++mi) {
#pragma unroll
        for (int rr = 0; rr < 4; ++rr) {
            int row = m0 + wm + mi * 16 + quad * 4 + rr;
            float* Crow = C + (size_t)row * DMODEL + n0 + wn + lrow;
#pragma unroll
            for (int ni = 0; ni < 4; ++ni)
                Crow[ni * 16] = acc[mi][ni][rr];
        }
    }
}

// MFMA sliding-window attention, 128-query blocks (8 waves, 512 thr).
// Grid 512 = exactly 2 blocks/CU, one balanced round. LDS 75 KB:
// KsP union (Ks 256x64 phase 1 / P 8x16x168 phase 2) + Vt 64x264.
__global__ __launch_bounds__(512) void attn_kernel(
    const __hip_bfloat16* __restrict__ Q,
    const __hip_bfloat16* __restrict__ K,
    const __hip_bfloat16* __restrict__ V,
    __hip_bfloat16* __restrict__ O)
{
    const int qb = blockIdx.x * 128;
    const int h  = blockIdx.y;
    const int b  = blockIdx.z;

    __shared__ __hip_bfloat16 KsP[8 * 16 * 168];  // >= 256*64; P overlay later
    __shared__ __hip_bfloat16 Vt[64 * 264];       // V^T, swizzled key blocks

    const size_t base = ((size_t)b * T_SEQ) * DMODEL + h * HDIM;
    const int t    = threadIdx.x;
    const int lane = t & 63;
    const int w    = t >> 6;                      // wave 0..7

    // K staging via DMA: wave w covers rows [w*32, w*32+32), 4 insts of 8 rows.
    {
        const int drow = lane >> 3, sl = lane & 7;
#pragma unroll
        for (int inst = 0; inst < 4; inst++) {
            int r0 = w * 32 + inst * 8;
            int r  = r0 + drow;
            int gcx = (sl - r) & 7;
            int j  = min(qb + r, T_SEQ - 1);
            gld_lds16(K + base + (size_t)j * DMODEL + gcx * 8, &KsP[r0 * 64]);
        }
    }
    // V staging: 256 tasks (dim-chunk c, key-block b0), 8x8 register transpose,
    // swizzled b128 writes: sg = (b0&~7)|((b0+c)&7).
    if (t < 256) {
        int c  = t & 7;
        int b0 = t >> 3;              // 0..31
        int sg = (b0 & ~7) | ((b0 + c) & 7);
        unsigned short m[8][8];
#pragma unroll
        for (int i = 0; i < 8; i++) {
            int j = min(qb + b0 * 8 + i, T_SEQ - 1);
            uint4 u = *(const uint4*)(V + base + (size_t)j * DMODEL + c * 8);
            unsigned short tmp[8];
            *(uint4*)tmp = u;
#pragma unroll
            for (int e = 0; e < 8; e++) m[e][i] = tmp[e];
        }
#pragma unroll
        for (int e = 0; e < 8; e++)
            *(uint4*)&Vt[(c * 8 + e) * 264 + sg * 8] = *(uint4*)m[e];
    }
    // zero tail slot 32 (keys >= 256; P is zero there but data must be finite)
    if (t < 64) {
        uint4 zz = {0, 0, 0, 0};
        *(uint4*)&Vt[t * 264 + 256] = zz;
    }
    __syncthreads();

    const int col  = lane & 15;
    const int quad = lane >> 4;
    const float slope = exp2f(-8.0f * (float)h / 15.0f);

    const __hip_bfloat16* qp = Q + base + (size_t)(qb + w * 16 + col) * DMODEL + quad * 8;
    bf16x8 qf0 = *(const bf16x8*)(qp);
    bf16x8 qf1 = *(const bf16x8*)(qp + 32);

    f32x4 sc[9];
#pragma unroll
    for (int kt = 0; kt < 9; kt++) {
        sc[kt] = (f32x4){0.f, 0.f, 0.f, 0.f};
        int r = w * 16 + kt * 16 + col;
        bf16x8 kb0 = *(const bf16x8*)&KsP[r * 64 + ((quad     + r) & 7) * 8];
        bf16x8 kb1 = *(const bf16x8*)&KsP[r * 64 + ((quad + 4 + r) & 7) * 8];
        sc[kt] = __builtin_amdgcn_mfma_f32_16x16x32_bf16(qf0, kb0, sc[kt], 0, 0, 0);
        sc[kt] = __builtin_amdgcn_mfma_f32_16x16x32_bf16(qf1, kb1, sc[kt], 0, 0, 0);
    }

    float mx[4] = {-3e38f, -3e38f, -3e38f, -3e38f};
#pragma unroll
    for (int kt = 0; kt < 9; kt++) {
#pragma unroll
        for (int r = 0; r < 4; r++) {
            int ql  = quad * 4 + r;
            int rel = kt * 16 + col - ql;
            int ka  = qb + w * 16 + kt * 16 + col;
            bool valid = (rel >= 0) && (rel < WINDOW) && (ka < T_SEQ);
            float v = valid ? (sc[kt][r] - (float)rel * slope) : -1e30f;
            sc[kt][r] = v;
            mx[r] = fmaxf(mx[r], v);
        }
    }
#pragma unroll
    for (int r = 0; r < 4; r++) {
        mx[r] = fmaxf(mx[r], __shfl_xor(mx[r], 1));
        mx[r] = fmaxf(mx[r], __shfl_xor(mx[r], 2));
        mx[r] = fmaxf(mx[r], __shfl_xor(mx[r], 4));
        mx[r] = fmaxf(mx[r], __shfl_xor(mx[r], 8));
    }
    float sm[4] = {0.f, 0.f, 0.f, 0.f};
#pragma unroll
    for (int kt = 0; kt < 9; kt++) {
#pragma unroll
        for (int r = 0; r < 4; r++) {
            float e = __expf(sc[kt][r] - mx[r]);
            sc[kt][r] = e;
            sm[r] += e;
        }
    }
#pragma unroll
    for (int r = 0; r < 4; r++) {
        sm[r] += __shfl_xor(sm[r], 1);
        sm[r] += __shfl_xor(sm[r], 2);
        sm[r] += __shfl_xor(sm[r], 4);
        sm[r] += __shfl_xor(sm[r], 8);
        sm[r] = 1.0f / sm[r];
    }

    // all Ks reads done -> overlay P (per-wave region, stride 168)
    __syncthreads();
    __hip_bfloat16* Ps = KsP + w * (16 * 168);
#pragma unroll
    for (int kt = 0; kt < 9; kt++)
#pragma unroll
        for (int r = 0; r < 4; r++)
            Ps[(quad * 4 + r) * 168 + kt * 16 + col] = __float2bfloat16(sc[kt][r] * sm[r]);
#pragma unroll
    for (int i = 0; i < 4; i++)
        Ps[(lane & 15) * 168 + 144 + quad * 4 + i] = __float2bfloat16(0.f);
    __syncthreads();

    // PV: A = P[q][key], B = Vt[dim][key] (swizzled slots)
    f32x4 o[4];
#pragma unroll
    for (int nd = 0; nd < 4; nd++) o[nd] = (f32x4){0.f, 0.f, 0.f, 0.f};
#pragma unroll
    for (int kc = 0; kc < 5; kc++) {
        bf16x8 pf = *(const bf16x8*)&Ps[col * 168 + kc * 32 + quad * 8];
        int bblk = w * 2 + kc * 4 + quad;
#pragma unroll
        for (int nd = 0; nd < 4; nd++) {
            int d  = nd * 16 + col;
            int sg = (bblk < 32) ? ((bblk & ~7) | ((bblk + (d >> 3)) & 7)) : 32;
            bf16x8 vf = *(const bf16x8*)&Vt[d * 264 + sg * 8];
            o[nd] = __builtin_amdgcn_mfma_f32_16x16x32_bf16(pf, vf, o[nd], 0, 0, 0);
        }
    }

#pragma unroll
    for (int r = 0; r < 4; r++) {
        __hip_bfloat16* op = O + base + (size_t)(qb + w * 16 + quad * 4 + r) * DMODEL + col;
#pragma unroll
        for (int nd = 0; nd < 4; nd++)
            op[nd * 16] = __float2bfloat16(o[nd][r]);
    }
}

extern "C" void kernel_launch(void* const* d_in, const int* in_sizes, int n_in,
                              void* d_out, int out_size, void* d_ws, size_t ws_size,
                              hipStream_t stream)
{
    const float* x  = (const float*)d_in[0];
    const float* Wq = (const float*)d_in[1];
    const float* Wk = (const float*)d_in[2];
    const float* Wv = (const float*)d_in[3];
    const float* Wo = (const float*)d_in[4];
    float* out = (float*)d_out;

    const size_t MT = (size_t)BATCH * T_SEQ;          // 4096 rows
    __hip_bfloat16* Qw = (__hip_bfloat16*)d_ws;       // 8 MB each (bf16)
    __hip_bfloat16* Kw = Qw + MT * DMODEL;
    __hip_bfloat16* Vw = Kw + MT * DMODEL;
    __hip_bfloat16* XA = Vw + MT * DMODEL;            // xb (pre-attn) / AO (post-attn)
    __hip_bfloat16* Wb = XA + MT * DMODEL;            // 4 x 1M bf16 weights

    cvt_kernel<<<4096, 256, 0, stream>>>(x, Wq, Wk, Wv, Wo, XA, Wb);

    // fused QKV: packed weight rows [Wq;Wk;Wv] = 3072x1024, 32x24 = 768 blocks
    gemm_qkv<<<dim3(768), 256, 0, stream>>>(XA, Wb, Qw, Kw, Vw);

    dim3 g2(T_SEQ / 128, NHEADS, BATCH);
    attn_kernel<<<g2, 512, 0, stream>>>(Qw, Kw, Vw, XA);

    gemm_o<<<dim3(256), 256, 0, stream>>>(XA, Wb + 3 * 1024 * 1024, out);
}

// Round 6
// 150.656 us; speedup vs baseline: 1.0075x; 1.0075x over previous
//
#include <hip/hip_runtime.h>
#include <hip/hip_bf16.h>

#define T_SEQ   2048
#define BATCH   2
#define DMODEL  1024
#define NHEADS  16
#define HDIM    64
#define WINDOW  128

typedef __attribute__((ext_vector_type(8))) short bf16x8;
typedef __attribute__((ext_vector_type(4))) float f32x4;

#define LGKM(n)  asm volatile("s_waitcnt lgkmcnt(" #n ")" ::: "memory")
#define VMCNT(n) asm volatile("s_waitcnt vmcnt(" #n ")" ::: "memory")
#define SCHEDB() __builtin_amdgcn_sched_barrier(0)
#define BAR()    __builtin_amdgcn_s_barrier()

// async global->LDS 16B per lane; LDS dest = wave-uniform base + lane*16
__device__ inline void gld_lds16(const __hip_bfloat16* g, __hip_bfloat16* l) {
    __builtin_amdgcn_global_load_lds(
        (const __attribute__((address_space(1))) unsigned int*)g,
        (__attribute__((address_space(3))) unsigned int*)l, 16, 0, 0);
}

// inline-asm LDS read: invisible to the compiler's waitcnt pass (no auto
// vmcnt(0)/lgkm(0) drains). Manual counted waits own correctness.
__device__ inline bf16x8 ds_readb128(const __hip_bfloat16* p) {
    bf16x8 r;
    asm volatile("ds_read_b128 %0, %1"
                 : "=v"(r)
                 : "v"((const __attribute__((address_space(3))) __hip_bfloat16*)p));
    return r;
}

// fp32 -> bf16 bulk convert, exact 1D grid: lid<2048 -> x (4M elems),
// else 512 blocks per weight slot (1M each).
__global__ __launch_bounds__(256) void cvt_kernel(
    const float* __restrict__ x,  const float* __restrict__ Wq,
    const float* __restrict__ Wk, const float* __restrict__ Wv,
    const float* __restrict__ Wo,
    __hip_bfloat16* __restrict__ xb, __hip_bfloat16* __restrict__ Wb)
{
    const int lid = blockIdx.x;
    const float* src;
    __hip_bfloat16* dst;
    int blk;
    if (lid < 2048) { src = x; dst = xb; blk = lid; }
    else {
        int slot = (lid - 2048) >> 9;           // 0..3
        blk = (lid - 2048) & 511;
        src = (slot == 0) ? Wq : (slot == 1) ? Wk : (slot == 2) ? Wv : Wo;
        dst = Wb + (size_t)slot * 1024 * 1024;
    }
    int i = (blk * 256 + threadIdx.x) * 8;
    float4 a = *(const float4*)(src + i);
    float4 b = *(const float4*)(src + i + 4);
    __hip_bfloat16 pk[8] = {
        __float2bfloat16(a.x), __float2bfloat16(a.y),
        __float2bfloat16(a.z), __float2bfloat16(a.w),
        __float2bfloat16(b.x), __float2bfloat16(b.y),
        __float2bfloat16(b.z), __float2bfloat16(b.w)};
    *(uint4*)(dst + i) = *(uint4*)pk;
}

// ---------------------------------------------------------------------------
// QKV GEMM v5 (kept from R5, numerically verified): 128x128 tile, 4 waves
// (64x64/wave), BK=64, 2-buffer 64KB LDS -> 2 blocks/CU antiphase.
// Grid 768 (32 bm x 24 bn), bijective XCD remap (96 blocks/XCD).
// 8-chunk rotation: slot s of row r holds k-chunk (s-r)&7, read (kc+r)&7
// (0 bank conflicts measured R1-R3). Gates per tile:
//   LGKM(8) before MFMA kk0; VMCNT(0)+LGKM(0)+BAR mid; tail reads next kk0.
// ---------------------------------------------------------------------------
__global__ __launch_bounds__(256, 2) void gemm_qkv(
    const __hip_bfloat16* __restrict__ A,
    const __hip_bfloat16* __restrict__ Wp,   // packed [Wq;Wk;Wv] = [3072,1024]
    __hip_bfloat16* __restrict__ C0,
    __hip_bfloat16* __restrict__ C1,
    __hip_bfloat16* __restrict__ C2)
{
    const int lid   = blockIdx.x;
    const int wgid  = (lid & 7) * 96 + (lid >> 3);   // 768 % 8 == 0: bijective
    const int bn    = wgid % 24;
    const int bm    = wgid / 24;
    const int m0    = bm * 128;
    const int n0    = bn * 128;
    const int z     = n0 >> 10;          // 0=Q 1=K 2=V (128 | 1024: no straddle)
    const int cbase = n0 & 1023;

    __shared__ __hip_bfloat16 S[2][2][128 * 64];   // [buf][A=0/B=1], 64 KiB

    const int t    = threadIdx.x;
    const int lane = t & 63;
    const int wv   = t >> 6;       // wave 0..3
    const int lrow = lane & 15;
    const int quad = lane >> 4;
    const int wm   = (wv >> 1) * 64;
    const int wn   = (wv & 1) * 64;
    const int drow = lane >> 3;
    const int sl   = lane & 7;

    f32x4 acc[4][4];
#pragma unroll
    for (int i = 0; i < 4; ++i)
#pragma unroll
        for (int j = 0; j < 4; ++j)
            acc[i][j] = (f32x4){0.f, 0.f, 0.f, 0.f};

    auto STAGE = [&](int tile, int buf) {
        const int k0 = tile << 6;
#pragma unroll
        for (int inst = 0; inst < 4; ++inst) {
            int r0 = wv * 32 + inst * 8;
            int r  = r0 + drow;
            int gcx = (sl - r) & 7;
            gld_lds16(A + (size_t)(m0 + r) * DMODEL + k0 + gcx * 8,
                      &S[buf][0][r0 * 64]);
        }
#pragma unroll
        for (int inst = 0; inst < 4; ++inst) {
            int r0 = wv * 32 + inst * 8;
            int r  = r0 + drow;
            int gcx = (sl - r) & 7;
            gld_lds16(Wp + (size_t)(n0 + r) * DMODEL + k0 + gcx * 8,
                      &S[buf][1][r0 * 64]);
        }
    };

    auto RDA = [&](int buf, int mi, int kc) -> bf16x8 {
        int r = wm + mi * 16 + lrow;
        return ds_readb128(&S[buf][0][r * 64 + (((kc + r) & 7) << 3)]);
    };
    auto RDB = [&](int buf, int ni, int kc) -> bf16x8 {
        int r = wn + ni * 16 + lrow;
        return ds_readb128(&S[buf][1][r * 64 + (((kc + r) & 7) << 3)]);
    };

    bf16x8 a0[4], b0[4], a1[4], b1[4];

    STAGE(0, 0);
    VMCNT(0);
    BAR();
#pragma unroll
    for (int mi = 0; mi < 4; ++mi) a0[mi] = RDA(0, mi, quad);
#pragma unroll
    for (int ni = 0; ni < 4; ++ni) b0[ni] = RDB(0, ni, quad);

#pragma unroll 2
    for (int tt = 0; tt < 16; ++tt) {
        const int cur = tt & 1, nxt = cur ^ 1;
        if (tt < 15) STAGE(tt + 1, nxt);
#pragma unroll
        for (int mi = 0; mi < 4; ++mi) a1[mi] = RDA(cur, mi, 4 + quad);
#pragma unroll
        for (int ni = 0; ni < 4; ++ni) b1[ni] = RDB(cur, ni, 4 + quad);
        LGKM(8); SCHEDB();
        __builtin_amdgcn_s_setprio(1);
#pragma unroll
        for (int mi = 0; mi < 4; ++mi)
#pragma unroll
            for (int ni = 0; ni < 4; ++ni)
                acc[mi][ni] = __builtin_amdgcn_mfma_f32_16x16x32_bf16(
                    a0[mi], b0[ni], acc[mi][ni], 0, 0, 0);
        __builtin_amdgcn_s_setprio(0);
        VMCNT(0);
        LGKM(0); SCHEDB();
        BAR();
        if (tt < 15) {
#pragma unroll
            for (int mi = 0; mi < 4; ++mi) a0[mi] = RDA(nxt, mi, quad);
#pragma unroll
            for (int ni = 0; ni < 4; ++ni) b0[ni] = RDB(nxt, ni, quad);
        }
        __builtin_amdgcn_s_setprio(1);
#pragma unroll
        for (int mi = 0; mi < 4; ++mi)
#pragma unroll
            for (int ni = 0; ni < 4; ++ni)
                acc[mi][ni] = __builtin_amdgcn_mfma_f32_16x16x32_bf16(
                    a1[mi], b1[ni], acc[mi][ni], 0, 0, 0);
        __builtin_amdgcn_s_setprio(0);
    }

    // per-head l2norm for Q,K (wave cols = exactly one 64-wide head)
    if (z != 2) {
#pragma unroll
        for (int mi = 0; mi < 4; ++mi) {
#pragma unroll
            for (int rr = 0; rr < 4; ++rr) {
                float ss = 0.f;
#pragma unroll
                for (int ni = 0; ni < 4; ++ni)
                    ss += acc[mi][ni][rr] * acc[mi][ni][rr];
                ss += __shfl_xor(ss, 1);
                ss += __shfl_xor(ss, 2);
                ss += __shfl_xor(ss, 4);
                ss += __shfl_xor(ss, 8);
                float inv = 1.0f / fmaxf(sqrtf(ss), 1e-6f);
#pragma unroll
                for (int ni = 0; ni < 4; ++ni)
                    acc[mi][ni][rr] *= inv;
            }
        }
    }

    __hip_bfloat16* C = (z == 0) ? C0 : (z == 1) ? C1 : C2;
#pragma unroll
    for (int mi = 0; mi < 4; ++mi) {
#pragma unroll
        for (int rr = 0; rr < 4; ++rr) {
            int row = m0 + wm + mi * 16 + quad * 4 + rr;
            __hip_bfloat16* Crow = C + (size_t)row * DMODEL + cbase + wn + lrow;
#pragma unroll
            for (int ni = 0; ni < 4; ++ni)
                Crow[ni * 16] = __float2bfloat16(acc[mi][ni][rr]);
        }
    }
}

// ---------------------------------------------------------------------------
// O-projection GEMM v6: exact clone of the verified R5-qkv structure
// (128x128, 4 waves, BK=64, 2-buffer, 8-chunk rotation, counted gates,
// 2 barriers/tile) — replaces the 32-barrier/4-slot R4 machinery and its
// unproven r>>1 rotation. fp32 epilogue, no l2norm. Grid 256 (32x8),
// bijective XCD remap (32/XCD).
// ---------------------------------------------------------------------------
__global__ __launch_bounds__(256, 2) void gemm_o(
    const __hip_bfloat16* __restrict__ A,
    const __hip_bfloat16* __restrict__ W,
    float* __restrict__ C)
{
    const int lid  = blockIdx.x;
    const int wgid = (lid & 7) * 32 + (lid >> 3);   // 256 % 8 == 0: bijective
    const int bn   = wgid & 7;
    const int bm   = wgid >> 3;
    const int m0   = bm * 128;
    const int n0   = bn * 128;

    __shared__ __hip_bfloat16 S[2][2][128 * 64];   // 64 KiB

    const int t    = threadIdx.x;
    const int lane = t & 63;
    const int wv   = t >> 6;
    const int lrow = lane & 15;
    const int quad = lane >> 4;
    const int wm   = (wv >> 1) * 64;
    const int wn   = (wv & 1) * 64;
    const int drow = lane >> 3;
    const int sl   = lane & 7;

    f32x4 acc[4][4];
#pragma unroll
    for (int i = 0; i < 4; ++i)
#pragma unroll
        for (int j = 0; j < 4; ++j)
            acc[i][j] = (f32x4){0.f, 0.f, 0.f, 0.f};

    auto STAGE = [&](int tile, int buf) {
        const int k0 = tile << 6;
#pragma unroll
        for (int inst = 0; inst < 4; ++inst) {
            int r0 = wv * 32 + inst * 8;
            int r  = r0 + drow;
            int gcx = (sl - r) & 7;
            gld_lds16(A + (size_t)(m0 + r) * DMODEL + k0 + gcx * 8,
                      &S[buf][0][r0 * 64]);
        }
#pragma unroll
        for (int inst = 0; inst < 4; ++inst) {
            int r0 = wv * 32 + inst * 8;
            int r  = r0 + drow;
            int gcx = (sl - r) & 7;
            gld_lds16(W + (size_t)(n0 + r) * DMODEL + k0 + gcx * 8,
                      &S[buf][1][r0 * 64]);
        }
    };

    auto RDA = [&](int buf, int mi, int kc) -> bf16x8 {
        int r = wm + mi * 16 + lrow;
        return ds_readb128(&S[buf][0][r * 64 + (((kc + r) & 7) << 3)]);
    };
    auto RDB = [&](int buf, int ni, int kc) -> bf16x8 {
        int r = wn + ni * 16 + lrow;
        return ds_readb128(&S[buf][1][r * 64 + (((kc + r) & 7) << 3)]);
    };

    bf16x8 a0[4], b0[4], a1[4], b1[4];

    STAGE(0, 0);
    VMCNT(0);
    BAR();
#pragma unroll
    for (int mi = 0; mi < 4; ++mi) a0[mi] = RDA(0, mi, quad);
#pragma unroll
    for (int ni = 0; ni < 4; ++ni) b0[ni] = RDB(0, ni, quad);

#pragma unroll 2
    for (int tt = 0; tt < 16; ++tt) {
        const int cur = tt & 1, nxt = cur ^ 1;
        if (tt < 15) STAGE(tt + 1, nxt);
#pragma unroll
        for (int mi = 0; mi < 4; ++mi) a1[mi] = RDA(cur, mi, 4 + quad);
#pragma unroll
        for (int ni = 0; ni < 4; ++ni) b1[ni] = RDB(cur, ni, 4 + quad);
        LGKM(8); SCHEDB();
        __builtin_amdgcn_s_setprio(1);
#pragma unroll
        for (int mi = 0; mi < 4; ++mi)
#pragma unroll
            for (int ni = 0; ni < 4; ++ni)
                acc[mi][ni] = __builtin_amdgcn_mfma_f32_16x16x32_bf16(
                    a0[mi], b0[ni], acc[mi][ni], 0, 0, 0);
        __builtin_amdgcn_s_setprio(0);
        VMCNT(0);
        LGKM(0); SCHEDB();
        BAR();
        if (tt < 15) {
#pragma unroll
            for (int mi = 0; mi < 4; ++mi) a0[mi] = RDA(nxt, mi, quad);
#pragma unroll
            for (int ni = 0; ni < 4; ++ni) b0[ni] = RDB(nxt, ni, quad);
        }
        __builtin_amdgcn_s_setprio(1);
#pragma unroll
        for (int mi = 0; mi < 4; ++mi)
#pragma unroll
            for (int ni = 0; ni < 4; ++ni)
                acc[mi][ni] = __builtin_amdgcn_mfma_f32_16x16x32_bf16(
                    a1[mi], b1[ni], acc[mi][ni], 0, 0, 0);
        __builtin_amdgcn_s_setprio(0);
    }

#pragma unroll
    for (int mi = 0; mi < 4; ++mi) {
#pragma unroll
        for (int rr = 0; rr < 4; ++rr) {
            int row = m0 + wm + mi * 16 + quad * 4 + rr;
            float* Crow = C + (size_t)row * DMODEL + n0 + wn + lrow;
#pragma unroll
            for (int ni = 0; ni < 4; ++ni)
                Crow[ni * 16] = acc[mi][ni][rr];
        }
    }
}

// MFMA sliding-window attention, 128-query blocks (8 waves, 512 thr).
// R6: Q fragment loads issued BEFORE the staging barrier (hides ~900cy HBM
// latency under staging); V transpose-staging spread over all 512 threads
// (4 rows/thread, uint2 writes) instead of 256x8 — halves the load chain.
__global__ __launch_bounds__(512) void attn_kernel(
    const __hip_bfloat16* __restrict__ Q,
    const __hip_bfloat16* __restrict__ K,
    const __hip_bfloat16* __restrict__ V,
    __hip_bfloat16* __restrict__ O)
{
    const int qb = blockIdx.x * 128;
    const int h  = blockIdx.y;
    const int b  = blockIdx.z;

    __shared__ __hip_bfloat16 KsP[8 * 16 * 168];  // >= 256*64; P overlay later
    __shared__ __hip_bfloat16 Vt[64 * 264];       // V^T, swizzled key blocks

    const size_t base = ((size_t)b * T_SEQ) * DMODEL + h * HDIM;
    const int t    = threadIdx.x;
    const int lane = t & 63;
    const int w    = t >> 6;                      // wave 0..7
    const int col  = lane & 15;
    const int quad = lane >> 4;

    // K staging via DMA: wave w covers rows [w*32, w*32+32), 4 insts of 8 rows.
    {
        const int drow = lane >> 3, sl = lane & 7;
#pragma unroll
        for (int inst = 0; inst < 4; inst++) {
            int r0 = w * 32 + inst * 8;
            int r  = r0 + drow;
            int gcx = (sl - r) & 7;
            int j  = min(qb + r, T_SEQ - 1);
            gld_lds16(K + base + (size_t)j * DMODEL + gcx * 8, &KsP[r0 * 64]);
        }
    }

    // Q fragment loads: independent of staging — issue before the barrier.
    const __hip_bfloat16* qp = Q + base + (size_t)(qb + w * 16 + col) * DMODEL + quad * 8;
    bf16x8 qf0 = *(const bf16x8*)(qp);
    bf16x8 qf1 = *(const bf16x8*)(qp + 32);

    // V staging: 512 tasks (dim-chunk c, key-block b0, half hf), 8x4 register
    // transpose each, swizzled writes: sg = (b0&~7)|((b0+c)&7).
    {
        int c  = t & 7;
        int b0 = (t >> 3) & 31;
        int hf = t >> 8;              // 0..1
        int sg = (b0 & ~7) | ((b0 + c) & 7);
        unsigned short m[8][4];
#pragma unroll
        for (int i = 0; i < 4; i++) {
            int j = min(qb + b0 * 8 + hf * 4 + i, T_SEQ - 1);
            uint4 u = *(const uint4*)(V + base + (size_t)j * DMODEL + c * 8);
            unsigned short tmp[8];
            *(uint4*)tmp = u;
#pragma unroll
            for (int e = 0; e < 8; e++) m[e][i] = tmp[e];
        }
#pragma unroll
        for (int e = 0; e < 8; e++)
            *(uint2*)&Vt[(c * 8 + e) * 264 + sg * 8 + hf * 4] = *(uint2*)m[e];
    }
    // zero tail slot 32 (keys >= 256; P is zero there but data must be finite)
    if (t < 64) {
        uint4 zz = {0, 0, 0, 0};
        *(uint4*)&Vt[t * 264 + 256] = zz;
    }
    __syncthreads();

    const float slope = exp2f(-8.0f * (float)h / 15.0f);

    f32x4 sc[9];
#pragma unroll
    for (int kt = 0; kt < 9; kt++) {
        sc[kt] = (f32x4){0.f, 0.f, 0.f, 0.f};
        int r = w * 16 + kt * 16 + col;
        bf16x8 kb0 = *(const bf16x8*)&KsP[r * 64 + ((quad     + r) & 7) * 8];
        bf16x8 kb1 = *(const bf16x8*)&KsP[r * 64 + ((quad + 4 + r) & 7) * 8];
        sc[kt] = __builtin_amdgcn_mfma_f32_16x16x32_bf16(qf0, kb0, sc[kt], 0, 0, 0);
        sc[kt] = __builtin_amdgcn_mfma_f32_16x16x32_bf16(qf1, kb1, sc[kt], 0, 0, 0);
    }

    float mx[4] = {-3e38f, -3e38f, -3e38f, -3e38f};
#pragma unroll
    for (int kt = 0; kt < 9; kt++) {
#pragma unroll
        for (int r = 0; r < 4; r++) {
            int ql  = quad * 4 + r;
            int rel = kt * 16 + col - ql;
            int ka  = qb + w * 16 + kt * 16 + col;
            bool valid = (rel >= 0) && (rel < WINDOW) && (ka < T_SEQ);
            float v = valid ? (sc[kt][r] - (float)rel * slope) : -1e30f;
            sc[kt][r] = v;
            mx[r] = fmaxf(mx[r], v);
        }
    }
#pragma unroll
    for (int r = 0; r < 4; r++) {
        mx[r] = fmaxf(mx[r], __shfl_xor(mx[r], 1));
        mx[r] = fmaxf(mx[r], __shfl_xor(mx[r], 2));
        mx[r] = fmaxf(mx[r], __shfl_xor(mx[r], 4));
        mx[r] = fmaxf(mx[r], __shfl_xor(mx[r], 8));
    }
    float sm[4] = {0.f, 0.f, 0.f, 0.f};
#pragma unroll
    for (int kt = 0; kt < 9; kt++) {
#pragma unroll
        for (int r = 0; r < 4; r++) {
            float e = __expf(sc[kt][r] - mx[r]);
            sc[kt][r] = e;
            sm[r] += e;
        }
    }
#pragma unroll
    for (int r = 0; r < 4; r++) {
        sm[r] += __shfl_xor(sm[r], 1);
        sm[r] += __shfl_xor(sm[r], 2);
        sm[r] += __shfl_xor(sm[r], 4);
        sm[r] += __shfl_xor(sm[r], 8);
        sm[r] = 1.0f / sm[r];
    }

    // all Ks reads done -> overlay P (per-wave region, stride 168)
    __syncthreads();
    __hip_bfloat16* Ps = KsP + w * (16 * 168);
#pragma unroll
    for (int kt = 0; kt < 9; kt++)
#pragma unroll
        for (int r = 0; r < 4; r++)
            Ps[(quad * 4 + r) * 168 + kt * 16 + col] = __float2bfloat16(sc[kt][r] * sm[r]);
#pragma unroll
    for (int i = 0; i < 4; i++)
        Ps[(lane & 15) * 168 + 144 + quad * 4 + i] = __float2bfloat16(0.f);
    __syncthreads();

    // PV: A = P[q][key], B = Vt[dim][key] (swizzled slots)
    f32x4 o[4];
#pragma unroll
    for (int nd = 0; nd < 4; nd++) o[nd] = (f32x4){0.f, 0.f, 0.f, 0.f};
#pragma unroll
    for (int kc = 0; kc < 5; kc++) {
        bf16x8 pf = *(const bf16x8*)&Ps[col * 168 + kc * 32 + quad * 8];
        int bblk = w * 2 + kc * 4 + quad;
#pragma unroll
        for (int nd = 0; nd < 4; nd++) {
            int d  = nd * 16 + col;
            int sg = (bblk < 32) ? ((bblk & ~7) | ((bblk + (d >> 3)) & 7)) : 32;
            bf16x8 vf = *(const bf16x8*)&Vt[d * 264 + sg * 8];
            o[nd] = __builtin_amdgcn_mfma_f32_16x16x32_bf16(pf, vf, o[nd], 0, 0, 0);
        }
    }

#pragma unroll
    for (int r = 0; r < 4; r++) {
        __hip_bfloat16* op = O + base + (size_t)(qb + w * 16 + quad * 4 + r) * DMODEL + col;
#pragma unroll
        for (int nd = 0; nd < 4; nd++)
            op[nd * 16] = __float2bfloat16(o[nd][r]);
    }
}

extern "C" void kernel_launch(void* const* d_in, const int* in_sizes, int n_in,
                              void* d_out, int out_size, void* d_ws, size_t ws_size,
                              hipStream_t stream)
{
    const float* x  = (const float*)d_in[0];
    const float* Wq = (const float*)d_in[1];
    const float* Wk = (const float*)d_in[2];
    const float* Wv = (const float*)d_in[3];
    const float* Wo = (const float*)d_in[4];
    float* out = (float*)d_out;

    const size_t MT = (size_t)BATCH * T_SEQ;          // 4096 rows
    __hip_bfloat16* Qw = (__hip_bfloat16*)d_ws;       // 8 MB each (bf16)
    __hip_bfloat16* Kw = Qw + MT * DMODEL;
    __hip_bfloat16* Vw = Kw + MT * DMODEL;
    __hip_bfloat16* XA = Vw + MT * DMODEL;            // xb (pre-attn) / AO (post-attn)
    __hip_bfloat16* Wb = XA + MT * DMODEL;            // 4 x 1M bf16 weights

    cvt_kernel<<<4096, 256, 0, stream>>>(x, Wq, Wk, Wv, Wo, XA, Wb);

    // fused QKV: packed weight rows [Wq;Wk;Wv] = 3072x1024, 32x24 = 768 blocks
    gemm_qkv<<<dim3(768), 256, 0, stream>>>(XA, Wb, Qw, Kw, Vw);

    dim3 g2(T_SEQ / 128, NHEADS, BATCH);
    attn_kernel<<<g2, 512, 0, stream>>>(Qw, Kw, Vw, XA);

    gemm_o<<<dim3(256), 256, 0, stream>>>(XA, Wb + 3 * 1024 * 1024, out);
}

// Round 7
// 148.784 us; speedup vs baseline: 1.0202x; 1.0126x over previous
//
#include <hip/hip_runtime.h>
#include <hip/hip_bf16.h>

#define T_SEQ   2048
#define BATCH   2
#define DMODEL  1024
#define NHEADS  16
#define HDIM    64
#define WINDOW  128

typedef __attribute__((ext_vector_type(8))) short bf16x8;
typedef __attribute__((ext_vector_type(4))) float f32x4;

#define LGKM(n)  asm volatile("s_waitcnt lgkmcnt(" #n ")" ::: "memory")
#define VMCNT(n) asm volatile("s_waitcnt vmcnt(" #n ")" ::: "memory")
#define SCHEDB() __builtin_amdgcn_sched_barrier(0)
#define BAR()    __builtin_amdgcn_s_barrier()

// async global->LDS 16B per lane; LDS dest = wave-uniform base + lane*16
__device__ inline void gld_lds16(const __hip_bfloat16* g, __hip_bfloat16* l) {
    __builtin_amdgcn_global_load_lds(
        (const __attribute__((address_space(1))) unsigned int*)g,
        (__attribute__((address_space(3))) unsigned int*)l, 16, 0, 0);
}

// inline-asm LDS read: invisible to the compiler's waitcnt pass (no auto
// vmcnt(0)/lgkm(0) drains). Manual counted waits own correctness.
__device__ inline bf16x8 ds_readb128(const __hip_bfloat16* p) {
    bf16x8 r;
    asm volatile("ds_read_b128 %0, %1"
                 : "=v"(r)
                 : "v"((const __attribute__((address_space(3))) __hip_bfloat16*)p));
    return r;
}

// fp32 -> bf16 bulk convert, exact 1D grid: lid<2048 -> x (4M elems),
// else 512 blocks per weight slot (1M each).
__global__ __launch_bounds__(256) void cvt_kernel(
    const float* __restrict__ x,  const float* __restrict__ Wq,
    const float* __restrict__ Wk, const float* __restrict__ Wv,
    const float* __restrict__ Wo,
    __hip_bfloat16* __restrict__ xb, __hip_bfloat16* __restrict__ Wb)
{
    const int lid = blockIdx.x;
    const float* src;
    __hip_bfloat16* dst;
    int blk;
    if (lid < 2048) { src = x; dst = xb; blk = lid; }
    else {
        int slot = (lid - 2048) >> 9;           // 0..3
        blk = (lid - 2048) & 511;
        src = (slot == 0) ? Wq : (slot == 1) ? Wk : (slot == 2) ? Wv : Wo;
        dst = Wb + (size_t)slot * 1024 * 1024;
    }
    int i = (blk * 256 + threadIdx.x) * 8;
    float4 a = *(const float4*)(src + i);
    float4 b = *(const float4*)(src + i + 4);
    __hip_bfloat16 pk[8] = {
        __float2bfloat16(a.x), __float2bfloat16(a.y),
        __float2bfloat16(a.z), __float2bfloat16(a.w),
        __float2bfloat16(b.x), __float2bfloat16(b.y),
        __float2bfloat16(b.z), __float2bfloat16(b.w)};
    *(uint4*)(dst + i) = *(uint4*)pk;
}

// ---------------------------------------------------------------------------
// QKV GEMM v5 (frozen since R5, numerically verified): 128x128 tile, 4 waves
// (64x64/wave), BK=64, 2-buffer 64KB LDS -> 2 blocks/CU antiphase.
// Grid 768 (32 bm x 24 bn), bijective XCD remap (96 blocks/XCD).
// 8-chunk rotation: slot s of row r holds k-chunk (s-r)&7, read (kc+r)&7
// (0 bank conflicts measured R1-R3). Gates per tile:
//   LGKM(8) before MFMA kk0; VMCNT(0)+LGKM(0)+BAR mid; tail reads next kk0.
// ---------------------------------------------------------------------------
__global__ __launch_bounds__(256, 2) void gemm_qkv(
    const __hip_bfloat16* __restrict__ A,
    const __hip_bfloat16* __restrict__ Wp,   // packed [Wq;Wk;Wv] = [3072,1024]
    __hip_bfloat16* __restrict__ C0,
    __hip_bfloat16* __restrict__ C1,
    __hip_bfloat16* __restrict__ C2)
{
    const int lid   = blockIdx.x;
    const int wgid  = (lid & 7) * 96 + (lid >> 3);   // 768 % 8 == 0: bijective
    const int bn    = wgid % 24;
    const int bm    = wgid / 24;
    const int m0    = bm * 128;
    const int n0    = bn * 128;
    const int z     = n0 >> 10;          // 0=Q 1=K 2=V (128 | 1024: no straddle)
    const int cbase = n0 & 1023;

    __shared__ __hip_bfloat16 S[2][2][128 * 64];   // [buf][A=0/B=1], 64 KiB

    const int t    = threadIdx.x;
    const int lane = t & 63;
    const int wv   = t >> 6;       // wave 0..3
    const int lrow = lane & 15;
    const int quad = lane >> 4;
    const int wm   = (wv >> 1) * 64;
    const int wn   = (wv & 1) * 64;
    const int drow = lane >> 3;
    const int sl   = lane & 7;

    f32x4 acc[4][4];
#pragma unroll
    for (int i = 0; i < 4; ++i)
#pragma unroll
        for (int j = 0; j < 4; ++j)
            acc[i][j] = (f32x4){0.f, 0.f, 0.f, 0.f};

    auto STAGE = [&](int tile, int buf) {
        const int k0 = tile << 6;
#pragma unroll
        for (int inst = 0; inst < 4; ++inst) {
            int r0 = wv * 32 + inst * 8;
            int r  = r0 + drow;
            int gcx = (sl - r) & 7;
            gld_lds16(A + (size_t)(m0 + r) * DMODEL + k0 + gcx * 8,
                      &S[buf][0][r0 * 64]);
        }
#pragma unroll
        for (int inst = 0; inst < 4; ++inst) {
            int r0 = wv * 32 + inst * 8;
            int r  = r0 + drow;
            int gcx = (sl - r) & 7;
            gld_lds16(Wp + (size_t)(n0 + r) * DMODEL + k0 + gcx * 8,
                      &S[buf][1][r0 * 64]);
        }
    };

    auto RDA = [&](int buf, int mi, int kc) -> bf16x8 {
        int r = wm + mi * 16 + lrow;
        return ds_readb128(&S[buf][0][r * 64 + (((kc + r) & 7) << 3)]);
    };
    auto RDB = [&](int buf, int ni, int kc) -> bf16x8 {
        int r = wn + ni * 16 + lrow;
        return ds_readb128(&S[buf][1][r * 64 + (((kc + r) & 7) << 3)]);
    };

    bf16x8 a0[4], b0[4], a1[4], b1[4];

    STAGE(0, 0);
    VMCNT(0);
    BAR();
#pragma unroll
    for (int mi = 0; mi < 4; ++mi) a0[mi] = RDA(0, mi, quad);
#pragma unroll
    for (int ni = 0; ni < 4; ++ni) b0[ni] = RDB(0, ni, quad);

#pragma unroll 2
    for (int tt = 0; tt < 16; ++tt) {
        const int cur = tt & 1, nxt = cur ^ 1;
        if (tt < 15) STAGE(tt + 1, nxt);
#pragma unroll
        for (int mi = 0; mi < 4; ++mi) a1[mi] = RDA(cur, mi, 4 + quad);
#pragma unroll
        for (int ni = 0; ni < 4; ++ni) b1[ni] = RDB(cur, ni, 4 + quad);
        LGKM(8); SCHEDB();
        __builtin_amdgcn_s_setprio(1);
#pragma unroll
        for (int mi = 0; mi < 4; ++mi)
#pragma unroll
            for (int ni = 0; ni < 4; ++ni)
                acc[mi][ni] = __builtin_amdgcn_mfma_f32_16x16x32_bf16(
                    a0[mi], b0[ni], acc[mi][ni], 0, 0, 0);
        __builtin_amdgcn_s_setprio(0);
        VMCNT(0);
        LGKM(0); SCHEDB();
        BAR();
        if (tt < 15) {
#pragma unroll
            for (int mi = 0; mi < 4; ++mi) a0[mi] = RDA(nxt, mi, quad);
#pragma unroll
            for (int ni = 0; ni < 4; ++ni) b0[ni] = RDB(nxt, ni, quad);
        }
        __builtin_amdgcn_s_setprio(1);
#pragma unroll
        for (int mi = 0; mi < 4; ++mi)
#pragma unroll
            for (int ni = 0; ni < 4; ++ni)
                acc[mi][ni] = __builtin_amdgcn_mfma_f32_16x16x32_bf16(
                    a1[mi], b1[ni], acc[mi][ni], 0, 0, 0);
        __builtin_amdgcn_s_setprio(0);
    }

    // per-head l2norm for Q,K (wave cols = exactly one 64-wide head)
    if (z != 2) {
#pragma unroll
        for (int mi = 0; mi < 4; ++mi) {
#pragma unroll
            for (int rr = 0; rr < 4; ++rr) {
                float ss = 0.f;
#pragma unroll
                for (int ni = 0; ni < 4; ++ni)
                    ss += acc[mi][ni][rr] * acc[mi][ni][rr];
                ss += __shfl_xor(ss, 1);
                ss += __shfl_xor(ss, 2);
                ss += __shfl_xor(ss, 4);
                ss += __shfl_xor(ss, 8);
                float inv = 1.0f / fmaxf(sqrtf(ss), 1e-6f);
#pragma unroll
                for (int ni = 0; ni < 4; ++ni)
                    acc[mi][ni][rr] *= inv;
            }
        }
    }

    __hip_bfloat16* C = (z == 0) ? C0 : (z == 1) ? C1 : C2;
#pragma unroll
    for (int mi = 0; mi < 4; ++mi) {
#pragma unroll
        for (int rr = 0; rr < 4; ++rr) {
            int row = m0 + wm + mi * 16 + quad * 4 + rr;
            __hip_bfloat16* Crow = C + (size_t)row * DMODEL + cbase + wn + lrow;
#pragma unroll
            for (int ni = 0; ni < 4; ++ni)
                Crow[ni * 16] = __float2bfloat16(acc[mi][ni][rr]);
        }
    }
}

// ---------------------------------------------------------------------------
// O-projection GEMM v7: 64x128 tile, grid 512 = 2 blocks/CU ANTIPHASE (the
// R5 mechanism gemm_o never had: at grid 256 it ran 1 block/CU in lockstep,
// ~21% MfmaUtil per the R4 measurement of that configuration).
// 4 waves (2x2, wave out 32x64), BK=64, 2-buffer 48KB LDS, proven 128B-row/
// 8-chunk rotation (0 conflicts R1-R3; the 64B/4-chunk variant measured
// 2.36M in R4 — do not revisit). Counted gate LGKM(6) (6 reads/kk-group).
// XCD remap: xcd gets bm stripe [x*8, x*8+8) x all bn — A 1MB, W 2MB per
// XCD L2. fp32 epilogue.
// ---------------------------------------------------------------------------
__global__ __launch_bounds__(256, 2) void gemm_o(
    const __hip_bfloat16* __restrict__ A,
    const __hip_bfloat16* __restrict__ W,
    float* __restrict__ C)
{
    const int lid  = blockIdx.x;
    const int wgid = (lid & 7) * 64 + (lid >> 3);   // 512 % 8 == 0: bijective
    const int bn   = wgid & 7;
    const int bm   = wgid >> 3;
    const int m0   = bm * 64;
    const int n0   = bn * 128;

    __shared__ __hip_bfloat16 SA[2][64 * 64];    // 16 KiB
    __shared__ __hip_bfloat16 SB[2][128 * 64];   // 32 KiB

    const int t    = threadIdx.x;
    const int lane = t & 63;
    const int wv   = t >> 6;       // 0..3
    const int lrow = lane & 15;
    const int quad = lane >> 4;
    const int wm   = (wv >> 1) * 32;
    const int wn   = (wv & 1) * 64;
    const int drow = lane >> 3;
    const int sl   = lane & 7;

    f32x4 acc[2][4];
#pragma unroll
    for (int i = 0; i < 2; ++i)
#pragma unroll
        for (int j = 0; j < 4; ++j)
            acc[i][j] = (f32x4){0.f, 0.f, 0.f, 0.f};

    auto STAGE = [&](int tile, int buf) {
        const int k0 = tile << 6;
#pragma unroll
        for (int inst = 0; inst < 2; ++inst) {
            int r0 = wv * 16 + inst * 8;
            int r  = r0 + drow;
            int gcx = (sl - r) & 7;
            gld_lds16(A + (size_t)(m0 + r) * DMODEL + k0 + gcx * 8,
                      &SA[buf][r0 * 64]);
        }
#pragma unroll
        for (int inst = 0; inst < 4; ++inst) {
            int r0 = wv * 32 + inst * 8;
            int r  = r0 + drow;
            int gcx = (sl - r) & 7;
            gld_lds16(W + (size_t)(n0 + r) * DMODEL + k0 + gcx * 8,
                      &SB[buf][r0 * 64]);
        }
    };

    auto RDA = [&](int buf, int mi, int kc) -> bf16x8 {
        int r = wm + mi * 16 + lrow;
        return ds_readb128(&SA[buf][r * 64 + (((kc + r) & 7) << 3)]);
    };
    auto RDB = [&](int buf, int ni, int kc) -> bf16x8 {
        int r = wn + ni * 16 + lrow;
        return ds_readb128(&SB[buf][r * 64 + (((kc + r) & 7) << 3)]);
    };

    bf16x8 a0[2], b0[4], a1[2], b1[4];

    STAGE(0, 0);
    VMCNT(0);
    BAR();
#pragma unroll
    for (int mi = 0; mi < 2; ++mi) a0[mi] = RDA(0, mi, quad);
#pragma unroll
    for (int ni = 0; ni < 4; ++ni) b0[ni] = RDB(0, ni, quad);

#pragma unroll 2
    for (int tt = 0; tt < 16; ++tt) {
        const int cur = tt & 1, nxt = cur ^ 1;
        if (tt < 15) STAGE(tt + 1, nxt);
#pragma unroll
        for (int mi = 0; mi < 2; ++mi) a1[mi] = RDA(cur, mi, 4 + quad);
#pragma unroll
        for (int ni = 0; ni < 4; ++ni) b1[ni] = RDB(cur, ni, 4 + quad);
        LGKM(6); SCHEDB();
        __builtin_amdgcn_s_setprio(1);
#pragma unroll
        for (int mi = 0; mi < 2; ++mi)
#pragma unroll
            for (int ni = 0; ni < 4; ++ni)
                acc[mi][ni] = __builtin_amdgcn_mfma_f32_16x16x32_bf16(
                    a0[mi], b0[ni], acc[mi][ni], 0, 0, 0);
        __builtin_amdgcn_s_setprio(0);
        VMCNT(0);
        LGKM(0); SCHEDB();
        BAR();
        if (tt < 15) {
#pragma unroll
            for (int mi = 0; mi < 2; ++mi) a0[mi] = RDA(nxt, mi, quad);
#pragma unroll
            for (int ni = 0; ni < 4; ++ni) b0[ni] = RDB(nxt, ni, quad);
        }
        __builtin_amdgcn_s_setprio(1);
#pragma unroll
        for (int mi = 0; mi < 2; ++mi)
#pragma unroll
            for (int ni = 0; ni < 4; ++ni)
                acc[mi][ni] = __builtin_amdgcn_mfma_f32_16x16x32_bf16(
                    a1[mi], b1[ni], acc[mi][ni], 0, 0, 0);
        __builtin_amdgcn_s_setprio(0);
    }

#pragma unroll
    for (int mi = 0; mi < 2; ++mi) {
#pragma unroll
        for (int rr = 0; rr < 4; ++rr) {
            int row = m0 + wm + mi * 16 + quad * 4 + rr;
            float* Crow = C + (size_t)row * DMODEL + n0 + wn + lrow;
#pragma unroll
            for (int ni = 0; ni < 4; ++ni)
                Crow[ni * 16] = acc[mi][ni][rr];
        }
    }
}

// MFMA sliding-window attention, 128-query blocks (8 waves, 512 thr).
// R6: Q fragment loads issued BEFORE the staging barrier (hides ~900cy HBM
// latency under staging); V transpose-staging spread over all 512 threads
// (4 rows/thread, uint2 writes) instead of 256x8 — halves the load chain.
__global__ __launch_bounds__(512) void attn_kernel(
    const __hip_bfloat16* __restrict__ Q,
    const __hip_bfloat16* __restrict__ K,
    const __hip_bfloat16* __restrict__ V,
    __hip_bfloat16* __restrict__ O)
{
    const int qb = blockIdx.x * 128;
    const int h  = blockIdx.y;
    const int b  = blockIdx.z;

    __shared__ __hip_bfloat16 KsP[8 * 16 * 168];  // >= 256*64; P overlay later
    __shared__ __hip_bfloat16 Vt[64 * 264];       // V^T, swizzled key blocks

    const size_t base = ((size_t)b * T_SEQ) * DMODEL + h * HDIM;
    const int t    = threadIdx.x;
    const int lane = t & 63;
    const int w    = t >> 6;                      // wave 0..7
    const int col  = lane & 15;
    const int quad = lane >> 4;

    // K staging via DMA: wave w covers rows [w*32, w*32+32), 4 insts of 8 rows.
    {
        const int drow = lane >> 3, sl = lane & 7;
#pragma unroll
        for (int inst = 0; inst < 4; inst++) {
            int r0 = w * 32 + inst * 8;
            int r  = r0 + drow;
            int gcx = (sl - r) & 7;
            int j  = min(qb + r, T_SEQ - 1);
            gld_lds16(K + base + (size_t)j * DMODEL + gcx * 8, &KsP[r0 * 64]);
        }
    }

    // Q fragment loads: independent of staging — issue before the barrier.
    const __hip_bfloat16* qp = Q + base + (size_t)(qb + w * 16 + col) * DMODEL + quad * 8;
    bf16x8 qf0 = *(const bf16x8*)(qp);
    bf16x8 qf1 = *(const bf16x8*)(qp + 32);

    // V staging: 512 tasks (dim-chunk c, key-block b0, half hf), 8x4 register
    // transpose each, swizzled writes: sg = (b0&~7)|((b0+c)&7).
    {
        int c  = t & 7;
        int b0 = (t >> 3) & 31;
        int hf = t >> 8;              // 0..1
        int sg = (b0 & ~7) | ((b0 + c) & 7);
        unsigned short m[8][4];
#pragma unroll
        for (int i = 0; i < 4; i++) {
            int j = min(qb + b0 * 8 + hf * 4 + i, T_SEQ - 1);
            uint4 u = *(const uint4*)(V + base + (size_t)j * DMODEL + c * 8);
            unsigned short tmp[8];
            *(uint4*)tmp = u;
#pragma unroll
            for (int e = 0; e < 8; e++) m[e][i] = tmp[e];
        }
#pragma unroll
        for (int e = 0; e < 8; e++)
            *(uint2*)&Vt[(c * 8 + e) * 264 + sg * 8 + hf * 4] = *(uint2*)m[e];
    }
    // zero tail slot 32 (keys >= 256; P is zero there but data must be finite)
    if (t < 64) {
        uint4 zz = {0, 0, 0, 0};
        *(uint4*)&Vt[t * 264 + 256] = zz;
    }
    __syncthreads();

    const float slope = exp2f(-8.0f * (float)h / 15.0f);

    f32x4 sc[9];
#pragma unroll
    for (int kt = 0; kt < 9; kt++) {
        sc[kt] = (f32x4){0.f, 0.f, 0.f, 0.f};
        int r = w * 16 + kt * 16 + col;
        bf16x8 kb0 = *(const bf16x8*)&KsP[r * 64 + ((quad     + r) & 7) * 8];
        bf16x8 kb1 = *(const bf16x8*)&KsP[r * 64 + ((quad + 4 + r) & 7) * 8];
        sc[kt] = __builtin_amdgcn_mfma_f32_16x16x32_bf16(qf0, kb0, sc[kt], 0, 0, 0);
        sc[kt] = __builtin_amdgcn_mfma_f32_16x16x32_bf16(qf1, kb1, sc[kt], 0, 0, 0);
    }

    float mx[4] = {-3e38f, -3e38f, -3e38f, -3e38f};
#pragma unroll
    for (int kt = 0; kt < 9; kt++) {
#pragma unroll
        for (int r = 0; r < 4; r++) {
            int ql  = quad * 4 + r;
            int rel = kt * 16 + col - ql;
            int ka  = qb + w * 16 + kt * 16 + col;
            bool valid = (rel >= 0) && (rel < WINDOW) && (ka < T_SEQ);
            float v = valid ? (sc[kt][r] - (float)rel * slope) : -1e30f;
            sc[kt][r] = v;
            mx[r] = fmaxf(mx[r], v);
        }
    }
#pragma unroll
    for (int r = 0; r < 4; r++) {
        mx[r] = fmaxf(mx[r], __shfl_xor(mx[r], 1));
        mx[r] = fmaxf(mx[r], __shfl_xor(mx[r], 2));
        mx[r] = fmaxf(mx[r], __shfl_xor(mx[r], 4));
        mx[r] = fmaxf(mx[r], __shfl_xor(mx[r], 8));
    }
    float sm[4] = {0.f, 0.f, 0.f, 0.f};
#pragma unroll
    for (int kt = 0; kt < 9; kt++) {
#pragma unroll
        for (int r = 0; r < 4; r++) {
            float e = __expf(sc[kt][r] - mx[r]);
            sc[kt][r] = e;
            sm[r] += e;
        }
    }
#pragma unroll
    for (int r = 0; r < 4; r++) {
        sm[r] += __shfl_xor(sm[r], 1);
        sm[r] += __shfl_xor(sm[r], 2);
        sm[r] += __shfl_xor(sm[r], 4);
        sm[r] += __shfl_xor(sm[r], 8);
        sm[r] = 1.0f / sm[r];
    }

    // all Ks reads done -> overlay P (per-wave region, stride 168)
    __syncthreads();
    __hip_bfloat16* Ps = KsP + w * (16 * 168);
#pragma unroll
    for (int kt = 0; kt < 9; kt++)
#pragma unroll
        for (int r = 0; r < 4; r++)
            Ps[(quad * 4 + r) * 168 + kt * 16 + col] = __float2bfloat16(sc[kt][r] * sm[r]);
#pragma unroll
    for (int i = 0; i < 4; i++)
        Ps[(lane & 15) * 168 + 144 + quad * 4 + i] = __float2bfloat16(0.f);
    __syncthreads();

    // PV: A = P[q][key], B = Vt[dim][key] (swizzled slots)
    f32x4 o[4];
#pragma unroll
    for (int nd = 0; nd < 4; nd++) o[nd] = (f32x4){0.f, 0.f, 0.f, 0.f};
#pragma unroll
    for (int kc = 0; kc < 5; kc++) {
        bf16x8 pf = *(const bf16x8*)&Ps[col * 168 + kc * 32 + quad * 8];
        int bblk = w * 2 + kc * 4 + quad;
#pragma unroll
        for (int nd = 0; nd < 4; nd++) {
            int d  = nd * 16 + col;
            int sg = (bblk < 32) ? ((bblk & ~7) | ((bblk + (d >> 3)) & 7)) : 32;
            bf16x8 vf = *(const bf16x8*)&Vt[d * 264 + sg * 8];
            o[nd] = __builtin_amdgcn_mfma_f32_16x16x32_bf16(pf, vf, o[nd], 0, 0, 0);
        }
    }

#pragma unroll
    for (int r = 0; r < 4; r++) {
        __hip_bfloat16* op = O + base + (size_t)(qb + w * 16 + quad * 4 + r) * DMODEL + col;
#pragma unroll
        for (int nd = 0; nd < 4; nd++)
            op[nd * 16] = __float2bfloat16(o[nd][r]);
    }
}

extern "C" void kernel_launch(void* const* d_in, const int* in_sizes, int n_in,
                              void* d_out, int out_size, void* d_ws, size_t ws_size,
                              hipStream_t stream)
{
    const float* x  = (const float*)d_in[0];
    const float* Wq = (const float*)d_in[1];
    const float* Wk = (const float*)d_in[2];
    const float* Wv = (const float*)d_in[3];
    const float* Wo = (const float*)d_in[4];
    float* out = (float*)d_out;

    const size_t MT = (size_t)BATCH * T_SEQ;          // 4096 rows
    __hip_bfloat16* Qw = (__hip_bfloat16*)d_ws;       // 8 MB each (bf16)
    __hip_bfloat16* Kw = Qw + MT * DMODEL;
    __hip_bfloat16* Vw = Kw + MT * DMODEL;
    __hip_bfloat16* XA = Vw + MT * DMODEL;            // xb (pre-attn) / AO (post-attn)
    __hip_bfloat16* Wb = XA + MT * DMODEL;            // 4 x 1M bf16 weights

    cvt_kernel<<<4096, 256, 0, stream>>>(x, Wq, Wk, Wv, Wo, XA, Wb);

    // fused QKV: packed weight rows [Wq;Wk;Wv] = 3072x1024, 32x24 = 768 blocks
    gemm_qkv<<<dim3(768), 256, 0, stream>>>(XA, Wb, Qw, Kw, Vw);

    dim3 g2(T_SEQ / 128, NHEADS, BATCH);
    attn_kernel<<<g2, 512, 0, stream>>>(Qw, Kw, Vw, XA);

    gemm_o<<<dim3(512), 256, 0, stream>>>(XA, Wb + 3 * 1024 * 1024, out);
}